// Round 7
// baseline (262.073 us; speedup 1.0000x reference)
//
#include <hip/hip_runtime.h>

// TTRCell: causal linear attention, chunked at C=128.
//   out_c = [tril(Q_c K_c^T) | Q_c] @ [V_c ; W_c],  W_c = sum_{cj<ci} (K^T V)_cj
// Two kernels: ttr_sums computes per-chunk S^T = V^T K (bf16, 16.8 MB ws);
// ttr_main reduces W in-block (L2/L3 reads), then does both GEMMs fused.

#define BH   64
#define SEQ  4096
#define FD   64
#define VD   64
#define C    128
#define NCH  (SEQ / C)   // 32

typedef __attribute__((ext_vector_type(8))) short  short8;
typedef __attribute__((ext_vector_type(4))) float  f32x4;

static __device__ __forceinline__ unsigned short f2bf(float f) {
    unsigned int u = __builtin_bit_cast(unsigned int, f);
    u += 0x7FFF + ((u >> 16) & 1);
    return (unsigned short)(u >> 16);
}
static __device__ __forceinline__ float bf2f(unsigned short h) {
    unsigned int u = ((unsigned int)h) << 16;
    return __builtin_bit_cast(float, u);
}
static __device__ __forceinline__ unsigned int pk2(float lo, float hi) {
    unsigned int a = __builtin_bit_cast(unsigned int, lo);
    unsigned int b = __builtin_bit_cast(unsigned int, hi);
    a += 0x7FFF + ((a >> 16) & 1);
    b += 0x7FFF + ((b >> 16) & 1);
    return (a >> 16) | (b & 0xFFFF0000u);
}

// ---------------------------------------------------------------------------
// Pass 1: ST[b][ci][v][f] = sum_{s in chunk} V[s][v] * K[s][f]
// grid: BH*NCH = 2048 blocks x 512 threads.
// ---------------------------------------------------------------------------
__global__ __launch_bounds__(512, 4) void ttr_sums(const float* __restrict__ k,
                                                   const float* __restrict__ v,
                                                   unsigned short* __restrict__ ST) {
    const int b  = blockIdx.x >> 5;
    const int ci = blockIdx.x & 31;
    __shared__ unsigned short KT[64][136];   // K^T[f][s]
    __shared__ unsigned short VT[64][136];   // V^T[v][s]
    __shared__ unsigned short Cs[64][72];    // coalescing buffer for output
    const int tid = threadIdx.x;
    const float* kc = k + ((size_t)b * SEQ + (size_t)ci * C) * FD;
    const float* vc = v + ((size_t)b * SEQ + (size_t)ci * C) * FD;

    // transpose-free staging: lane = f (coalesced 256B loads), pack 4 t's -> b64 write
    #pragma unroll
    for (int it = 0; it < 4; ++it) {
        const int i = tid + it * 512;
        const int f = i & 63, t4 = (i >> 6) << 2;
        float k0 = kc[(t4+0)*FD + f], k1 = kc[(t4+1)*FD + f];
        float k2 = kc[(t4+2)*FD + f], k3 = kc[(t4+3)*FD + f];
        float v0 = vc[(t4+0)*FD + f], v1 = vc[(t4+1)*FD + f];
        float v2 = vc[(t4+2)*FD + f], v3 = vc[(t4+3)*FD + f];
        uint2 kw, vw;
        kw.x = pk2(k0, k1); kw.y = pk2(k2, k3);
        vw.x = pk2(v0, v1); vw.y = pk2(v2, v3);
        *(uint2*)&KT[f][t4] = kw;
        *(uint2*)&VT[f][t4] = vw;
    }
    __syncthreads();

    const int wid  = tid >> 6;        // waves 0..3 compute; 4..7 idle past MFMA
    const int lane = tid & 63;
    const int mrow = lane & 15;
    const int kb   = (lane >> 4) << 3;

    if (wid < 4) {
        f32x4 acc[4] = {};
        #pragma unroll
        for (int ks = 0; ks < 4; ++ks) {
            short8 a = *(const short8*)&VT[16 * wid + mrow][ks * 32 + kb];
            #pragma unroll
            for (int cf = 0; cf < 4; ++cf) {
                short8 bb = *(const short8*)&KT[16 * cf + mrow][ks * 32 + kb];
                acc[cf] = __builtin_amdgcn_mfma_f32_16x16x32_bf16(a, bb, acc[cf], 0, 0, 0);
            }
        }
        // C layout: col = lane&15, row = (lane>>4)*4 + r
        const int vrow0 = 16 * wid + ((lane >> 4) << 2);
        const int fcol  = lane & 15;
        #pragma unroll
        for (int cf = 0; cf < 4; ++cf)
            #pragma unroll
            for (int r = 0; r < 4; ++r)
                Cs[vrow0 + r][cf * 16 + fcol] = f2bf(acc[cf][r]);
    }
    __syncthreads();

    // coalesced 16B store: 512 threads x 16B = 8KB chunk sum
    unsigned short* outp = ST + (size_t)(b * NCH + ci) * (VD * FD);
    const int rr = tid >> 3, c8 = (tid & 7) << 3;
    *(uint4*)(outp + rr * FD + c8) = *(const uint4*)&Cs[rr][c8];
}

// ---------------------------------------------------------------------------
// Pass 2 (fused): per chunk, W = sum_{cj<ci} S_cj (reduced in-block), then
// O = (tril(Q K^T) V + Q W) / (t+1) as [P|Q](128x192) @ [V^T;W^T](192x64).
// grid: 2048 blocks x 512 threads; XCD-swizzled so a head's chunks share L2.
// ---------------------------------------------------------------------------
__global__ __launch_bounds__(512, 4) void ttr_main(const float* __restrict__ q,
                                                   const float* __restrict__ k,
                                                   const float* __restrict__ v,
                                                   const unsigned short* __restrict__ ST,
                                                   float* __restrict__ out) {
    // bid -> (b, ci): all 32 chunks of head b land on XCD (b&7)
    const unsigned bid = blockIdx.x;
    const int b  = (int)(((bid & 7u) << 3) | (bid >> 8));
    const int ci = (int)((bid >> 3) & 31u);

    __shared__ unsigned short POOL[8 * 16 * 136];  // Ks[128][72] (GEMM1) ∪ Ps[8][16][136] (GEMM2)
    __shared__ unsigned short Qs[128][72];         // Q row-major
    __shared__ unsigned short VTs[64][200];        // [v][0..127]=V^T[v][s]; [v][128..191]=W^T[v][f]
    const int tid = threadIdx.x;
    const float* qc = q + ((size_t)b * SEQ + (size_t)ci * C) * FD;
    const float* kc = k + ((size_t)b * SEQ + (size_t)ci * C) * FD;
    const float* vc = v + ((size_t)b * SEQ + (size_t)ci * C) * FD;

    // ---- W-reduce: W^T[v][f] = sum_{cj<ci} S^T_cj, bf16 in / f32 acc ----
    {
        float wa[8] = {0.f, 0.f, 0.f, 0.f, 0.f, 0.f, 0.f, 0.f};
        const unsigned short* stb = ST + (size_t)b * NCH * (VD * FD) + tid * 8;
        for (int cj = 0; cj < ci; ++cj) {
            short8 s = *(const short8*)(stb + (size_t)cj * (VD * FD));
            #pragma unroll
            for (int j = 0; j < 8; ++j) wa[j] += bf2f((unsigned short)s[j]);
        }
        const int vv = tid >> 3, f0 = (tid & 7) << 3;
        uint4 wv;
        wv.x = pk2(wa[0], wa[1]); wv.y = pk2(wa[2], wa[3]);
        wv.z = pk2(wa[4], wa[5]); wv.w = pk2(wa[6], wa[7]);
        *(uint4*)&VTs[vv][128 + f0] = wv;
    }

    // ---- stage Q,K row-major: 8 consecutive f per thread -> one b128 write ----
    #pragma unroll
    for (int it = 0; it < 2; ++it) {
        const int i = tid + it * 512;
        const int t = i >> 3, f8 = (i & 7) << 3;
        float4 q0 = *(const float4*)(qc + t * FD + f8);
        float4 q1 = *(const float4*)(qc + t * FD + f8 + 4);
        float4 k0 = *(const float4*)(kc + t * FD + f8);
        float4 k1 = *(const float4*)(kc + t * FD + f8 + 4);
        uint4 qw, kw;
        qw.x = pk2(q0.x, q0.y); qw.y = pk2(q0.z, q0.w);
        qw.z = pk2(q1.x, q1.y); qw.w = pk2(q1.z, q1.w);
        kw.x = pk2(k0.x, k0.y); kw.y = pk2(k0.z, k0.w);
        kw.z = pk2(k1.x, k1.y); kw.w = pk2(k1.z, k1.w);
        *(uint4*)&Qs[t][f8] = qw;
        *(uint4*)&POOL[t * 72 + f8] = kw;       // Ks
    }

    // ---- stage V^T: lane = v (coalesced), pack 4 t's -> b64 write ----
    #pragma unroll
    for (int it = 0; it < 4; ++it) {
        const int i = tid + it * 512;
        const int f = i & 63, t4 = (i >> 6) << 2;
        float v0 = vc[(t4+0)*FD + f], v1 = vc[(t4+1)*FD + f];
        float v2 = vc[(t4+2)*FD + f], v3 = vc[(t4+3)*FD + f];
        uint2 vw;
        vw.x = pk2(v0, v1); vw.y = pk2(v2, v3);
        *(uint2*)&VTs[f][t4] = vw;
    }
    __syncthreads();

    const int wid  = tid >> 6;
    const int lane = tid & 63;
    const int mrow = lane & 15;
    const int kb   = (lane >> 4) << 3;

    // ---- GEMM1: P(16x128 per wave) = Q K^T ----
    f32x4 pacc[8] = {};
    #pragma unroll
    for (int ks = 0; ks < 2; ++ks) {
        short8 a = *(const short8*)&Qs[16 * wid + mrow][ks * 32 + kb];
        #pragma unroll
        for (int cf = 0; cf < 8; ++cf) {
            short8 bb = *(const short8*)&POOL[(16 * cf + mrow) * 72 + ks * 32 + kb];
            pacc[cf] = __builtin_amdgcn_mfma_f32_16x16x32_bf16(a, bb, pacc[cf], 0, 0, 0);
        }
    }
    __syncthreads();   // all waves done reading Ks before Ps overwrites POOL

    // ---- mask + store P slab (bf16) into POOL ----
    const int prow0 = (lane >> 4) << 2;
    const int pcol  = lane & 15;
    #pragma unroll
    for (int cf = 0; cf < 8; ++cf)
        #pragma unroll
        for (int r = 0; r < 4; ++r) {
            const int row_local = 16 * wid + prow0 + r;
            const int col       = 16 * cf + pcol;
            const float val = (col <= row_local) ? pacc[cf][r] : 0.f;
            POOL[(16 * wid + prow0 + r) * 136 + col] = f2bf(val);
        }
    __syncthreads();

    // ---- GEMM2: O(16x64 per wave) = [P | Q] @ [V^T ; W^T], k = 192 ----
    f32x4 oacc[4] = {};
    #pragma unroll
    for (int ks = 0; ks < 6; ++ks) {
        short8 a;
        if (ks < 4) a = *(const short8*)&POOL[(16 * wid + mrow) * 136 + ks * 32 + kb];
        else        a = *(const short8*)&Qs[16 * wid + mrow][(ks - 4) * 32 + kb];
        #pragma unroll
        for (int cn = 0; cn < 4; ++cn) {
            short8 bb = *(const short8*)&VTs[16 * cn + mrow][ks * 32 + kb];
            oacc[cn] = __builtin_amdgcn_mfma_f32_16x16x32_bf16(a, bb, oacc[cn], 0, 0, 0);
        }
    }

    // ---- epilogue: /(t+1), f32 store ----
    float* oc = out + ((size_t)b * SEQ + (size_t)ci * C) * VD;
    #pragma unroll
    for (int cn = 0; cn < 4; ++cn)
        #pragma unroll
        for (int r = 0; r < 4; ++r) {
            const int row_local = 16 * wid + prow0 + r;
            const float den = (float)(ci * C + row_local + 1);
            oc[(size_t)row_local * VD + cn * 16 + pcol] = oacc[cn][r] / den;
        }
}

// ---------------------------------------------------------------------------
extern "C" void kernel_launch(void* const* d_in, const int* in_sizes, int n_in,
                              void* d_out, int out_size, void* d_ws, size_t ws_size,
                              hipStream_t stream) {
    const float* q = (const float*)d_in[0];
    const float* k = (const float*)d_in[1];
    const float* v = (const float*)d_in[2];
    float* out = (float*)d_out;
    unsigned short* ST = (unsigned short*)d_ws;   // 64*32*4096*2B = 16.8 MB

    ttr_sums<<<BH * NCH, 512, 0, stream>>>(k, v, ST);
    ttr_main<<<BH * NCH, 512, 0, stream>>>(q, k, v, ST, out);
}

// Round 8
// 245.438 us; speedup vs baseline: 1.0678x; 1.0678x over previous
//
#include <hip/hip_runtime.h>

// TTRCell: causal linear attention, chunked at C=128.
//   out_c = [tril(Q_c K_c^T) | Q_c] @ [V_c ; W_c],  W_c = sum_{cj<ci} (K^T V)_cj
// Three kernels:
//   ttr_sums   : per-chunk S^T = V^T K  (bf16, 16.8 MB ws)
//   ttr_prefix : in-place exclusive prefix over the 32 chunks (vector short8)
//   ttr_main   : W^T = direct 8KB load; then [P|Q] @ [V^T;W^T] fused GEMMs
// R2 post-mortem: in-block W-reduce made ttr_main VALU/latency-bound
// (VALUBusy 25%, 81us). Moving the prefix back out, vectorized.

#define BH   64
#define SEQ  4096
#define FD   64
#define VD   64
#define C    128
#define NCH  (SEQ / C)   // 32

typedef __attribute__((ext_vector_type(8))) short  short8;
typedef __attribute__((ext_vector_type(4))) float  f32x4;

static __device__ __forceinline__ unsigned short f2bf(float f) {
    unsigned int u = __builtin_bit_cast(unsigned int, f);
    u += 0x7FFF + ((u >> 16) & 1);
    return (unsigned short)(u >> 16);
}
static __device__ __forceinline__ float bf2f(unsigned short h) {
    unsigned int u = ((unsigned int)h) << 16;
    return __builtin_bit_cast(float, u);
}
static __device__ __forceinline__ unsigned int pk2(float lo, float hi) {
    unsigned int a = __builtin_bit_cast(unsigned int, lo);
    unsigned int b = __builtin_bit_cast(unsigned int, hi);
    a += 0x7FFF + ((a >> 16) & 1);
    b += 0x7FFF + ((b >> 16) & 1);
    return (a >> 16) | (b & 0xFFFF0000u);
}

// ---------------------------------------------------------------------------
// Pass 1: ST[b][ci][v][f] = sum_{s in chunk} V[s][v] * K[s][f]
// grid: BH*NCH = 2048 blocks x 512 threads.
// ---------------------------------------------------------------------------
__global__ __launch_bounds__(512, 4) void ttr_sums(const float* __restrict__ k,
                                                   const float* __restrict__ v,
                                                   unsigned short* __restrict__ ST) {
    const int b  = blockIdx.x >> 5;
    const int ci = blockIdx.x & 31;
    __shared__ unsigned short KT[64][136];   // K^T[f][s]
    __shared__ unsigned short VT[64][136];   // V^T[v][s]
    __shared__ unsigned short Cs[64][72];    // coalescing buffer for output
    const int tid = threadIdx.x;
    const float* kc = k + ((size_t)b * SEQ + (size_t)ci * C) * FD;
    const float* vc = v + ((size_t)b * SEQ + (size_t)ci * C) * FD;

    // transpose-free staging: lane = f (coalesced 256B loads), pack 4 t's -> b64 write
    #pragma unroll
    for (int it = 0; it < 4; ++it) {
        const int i = tid + it * 512;
        const int f = i & 63, t4 = (i >> 6) << 2;
        float k0 = kc[(t4+0)*FD + f], k1 = kc[(t4+1)*FD + f];
        float k2 = kc[(t4+2)*FD + f], k3 = kc[(t4+3)*FD + f];
        float v0 = vc[(t4+0)*FD + f], v1 = vc[(t4+1)*FD + f];
        float v2 = vc[(t4+2)*FD + f], v3 = vc[(t4+3)*FD + f];
        uint2 kw, vw;
        kw.x = pk2(k0, k1); kw.y = pk2(k2, k3);
        vw.x = pk2(v0, v1); vw.y = pk2(v2, v3);
        *(uint2*)&KT[f][t4] = kw;
        *(uint2*)&VT[f][t4] = vw;
    }
    __syncthreads();

    const int wid  = tid >> 6;        // waves 0..3 compute; 4..7 idle past MFMA
    const int lane = tid & 63;
    const int mrow = lane & 15;
    const int kb   = (lane >> 4) << 3;

    if (wid < 4) {
        f32x4 acc[4] = {};
        #pragma unroll
        for (int ks = 0; ks < 4; ++ks) {
            short8 a = *(const short8*)&VT[16 * wid + mrow][ks * 32 + kb];
            #pragma unroll
            for (int cf = 0; cf < 4; ++cf) {
                short8 bb = *(const short8*)&KT[16 * cf + mrow][ks * 32 + kb];
                acc[cf] = __builtin_amdgcn_mfma_f32_16x16x32_bf16(a, bb, acc[cf], 0, 0, 0);
            }
        }
        // C layout: col = lane&15, row = (lane>>4)*4 + r
        const int vrow0 = 16 * wid + ((lane >> 4) << 2);
        const int fcol  = lane & 15;
        #pragma unroll
        for (int cf = 0; cf < 4; ++cf)
            #pragma unroll
            for (int r = 0; r < 4; ++r)
                Cs[vrow0 + r][cf * 16 + fcol] = f2bf(acc[cf][r]);
    }
    __syncthreads();

    // coalesced 16B store: 512 threads x 16B = 8KB chunk sum
    unsigned short* outp = ST + (size_t)(b * NCH + ci) * (VD * FD);
    const int rr = tid >> 3, c8 = (tid & 7) << 3;
    *(uint4*)(outp + rr * FD + c8) = *(const uint4*)&Cs[rr][c8];
}

// ---------------------------------------------------------------------------
// Pass 2: in-place exclusive prefix over chunks, vectorized short8.
// grid: 128 blocks x 256 threads; each thread owns 8 consecutive elements of
// one head and walks the 32 chunks serially (f32 accumulate, bf16 store).
// ---------------------------------------------------------------------------
__global__ __launch_bounds__(256) void ttr_prefix(unsigned short* __restrict__ ST) {
    const int gtid = blockIdx.x * 256 + threadIdx.x;     // 0..32767
    const int b    = gtid >> 9;                          // head (512 threads/head)
    const int off  = (gtid & 511) << 3;                  // element offset 0..4088
    unsigned short* p = ST + (size_t)b * NCH * (VD * FD) + off;
    float acc[8] = {0.f, 0.f, 0.f, 0.f, 0.f, 0.f, 0.f, 0.f};
    #pragma unroll 8
    for (int ci = 0; ci < NCH; ++ci) {
        unsigned short* pc = p + (size_t)ci * (VD * FD);
        short8 s = *(const short8*)pc;
        uint4 w;
        w.x = pk2(acc[0], acc[1]); w.y = pk2(acc[2], acc[3]);
        w.z = pk2(acc[4], acc[5]); w.w = pk2(acc[6], acc[7]);
        *(uint4*)pc = w;                                 // exclusive: write before add
        #pragma unroll
        for (int j = 0; j < 8; ++j) acc[j] += bf2f((unsigned short)s[j]);
    }
}

// ---------------------------------------------------------------------------
// Pass 3: per chunk, O = (tril(Q K^T) V + Q W) / (t+1)
// as [P|Q](128x192) @ [V^T;W^T](192x64).  W^T is a direct 8KB load now.
// grid: 2048 blocks x 512 threads; XCD-swizzled so a head's chunks share L2.
// ---------------------------------------------------------------------------
__global__ __launch_bounds__(512, 4) void ttr_main(const float* __restrict__ q,
                                                   const float* __restrict__ k,
                                                   const float* __restrict__ v,
                                                   const unsigned short* __restrict__ WT,
                                                   float* __restrict__ out) {
    // bid -> (b, ci): all 32 chunks of head b land on XCD (b&7)
    const unsigned bid = blockIdx.x;
    const int b  = (int)(((bid & 7u) << 3) | (bid >> 8));
    const int ci = (int)((bid >> 3) & 31u);

    __shared__ unsigned short POOL[8 * 16 * 136];  // Ks[128][72] (GEMM1) ∪ Ps[8][16][136] (GEMM2)
    __shared__ unsigned short Qs[128][72];         // Q row-major
    __shared__ unsigned short VTs[64][200];        // [v][0..127]=V^T[v][s]; [v][128..191]=W^T[v][f]
    const int tid = threadIdx.x;
    const float* qc = q + ((size_t)b * SEQ + (size_t)ci * C) * FD;
    const float* kc = k + ((size_t)b * SEQ + (size_t)ci * C) * FD;
    const float* vc = v + ((size_t)b * SEQ + (size_t)ci * C) * FD;

    // ---- W^T: direct 8KB coalesced copy (prefix already done) ----
    {
        const unsigned short* wsrc = WT + (size_t)(b * NCH + ci) * (VD * FD);
        const int vv = tid >> 3, f0 = (tid & 7) << 3;
        *(uint4*)&VTs[vv][128 + f0] = *(const uint4*)(wsrc + tid * 8);
    }

    // ---- stage Q,K row-major: 8 consecutive f per thread -> one b128 write ----
    #pragma unroll
    for (int it = 0; it < 2; ++it) {
        const int i = tid + it * 512;
        const int t = i >> 3, f8 = (i & 7) << 3;
        float4 q0 = *(const float4*)(qc + t * FD + f8);
        float4 q1 = *(const float4*)(qc + t * FD + f8 + 4);
        float4 k0 = *(const float4*)(kc + t * FD + f8);
        float4 k1 = *(const float4*)(kc + t * FD + f8 + 4);
        uint4 qw, kw;
        qw.x = pk2(q0.x, q0.y); qw.y = pk2(q0.z, q0.w);
        qw.z = pk2(q1.x, q1.y); qw.w = pk2(q1.z, q1.w);
        kw.x = pk2(k0.x, k0.y); kw.y = pk2(k0.z, k0.w);
        kw.z = pk2(k1.x, k1.y); kw.w = pk2(k1.z, k1.w);
        *(uint4*)&Qs[t][f8] = qw;
        *(uint4*)&POOL[t * 72 + f8] = kw;       // Ks
    }

    // ---- stage V^T: lane = v (coalesced), pack 4 t's -> b64 write ----
    #pragma unroll
    for (int it = 0; it < 4; ++it) {
        const int i = tid + it * 512;
        const int f = i & 63, t4 = (i >> 6) << 2;
        float v0 = vc[(t4+0)*FD + f], v1 = vc[(t4+1)*FD + f];
        float v2 = vc[(t4+2)*FD + f], v3 = vc[(t4+3)*FD + f];
        uint2 vw;
        vw.x = pk2(v0, v1); vw.y = pk2(v2, v3);
        *(uint2*)&VTs[f][t4] = vw;
    }
    __syncthreads();

    const int wid  = tid >> 6;
    const int lane = tid & 63;
    const int mrow = lane & 15;
    const int kb   = (lane >> 4) << 3;

    // ---- GEMM1: P(16x128 per wave) = Q K^T ----
    f32x4 pacc[8] = {};
    #pragma unroll
    for (int ks = 0; ks < 2; ++ks) {
        short8 a = *(const short8*)&Qs[16 * wid + mrow][ks * 32 + kb];
        #pragma unroll
        for (int cf = 0; cf < 8; ++cf) {
            short8 bb = *(const short8*)&POOL[(16 * cf + mrow) * 72 + ks * 32 + kb];
            pacc[cf] = __builtin_amdgcn_mfma_f32_16x16x32_bf16(a, bb, pacc[cf], 0, 0, 0);
        }
    }
    __syncthreads();   // all waves done reading Ks before Ps overwrites POOL

    // ---- mask + store P slab (bf16) into POOL ----
    const int prow0 = (lane >> 4) << 2;
    const int pcol  = lane & 15;
    #pragma unroll
    for (int cf = 0; cf < 8; ++cf)
        #pragma unroll
        for (int r = 0; r < 4; ++r) {
            const int row_local = 16 * wid + prow0 + r;
            const int col       = 16 * cf + pcol;
            const float val = (col <= row_local) ? pacc[cf][r] : 0.f;
            POOL[(16 * wid + prow0 + r) * 136 + col] = f2bf(val);
        }
    __syncthreads();

    // ---- GEMM2: O(16x64 per wave) = [P | Q] @ [V^T ; W^T], k = 192 ----
    f32x4 oacc[4] = {};
    #pragma unroll
    for (int ks = 0; ks < 6; ++ks) {
        short8 a;
        if (ks < 4) a = *(const short8*)&POOL[(16 * wid + mrow) * 136 + ks * 32 + kb];
        else        a = *(const short8*)&Qs[16 * wid + mrow][(ks - 4) * 32 + kb];
        #pragma unroll
        for (int cn = 0; cn < 4; ++cn) {
            short8 bb = *(const short8*)&VTs[16 * cn + mrow][ks * 32 + kb];
            oacc[cn] = __builtin_amdgcn_mfma_f32_16x16x32_bf16(a, bb, oacc[cn], 0, 0, 0);
        }
    }

    // ---- epilogue: /(t+1), f32 store ----
    float* oc = out + ((size_t)b * SEQ + (size_t)ci * C) * VD;
    #pragma unroll
    for (int cn = 0; cn < 4; ++cn)
        #pragma unroll
        for (int r = 0; r < 4; ++r) {
            const int row_local = 16 * wid + prow0 + r;
            const float den = (float)(ci * C + row_local + 1);
            oc[(size_t)row_local * VD + cn * 16 + pcol] = oacc[cn][r] / den;
        }
}

// ---------------------------------------------------------------------------
extern "C" void kernel_launch(void* const* d_in, const int* in_sizes, int n_in,
                              void* d_out, int out_size, void* d_ws, size_t ws_size,
                              hipStream_t stream) {
    const float* q = (const float*)d_in[0];
    const float* k = (const float*)d_in[1];
    const float* v = (const float*)d_in[2];
    float* out = (float*)d_out;
    unsigned short* ST = (unsigned short*)d_ws;   // 64*32*4096*2B = 16.8 MB

    ttr_sums<<<BH * NCH, 512, 0, stream>>>(k, v, ST);
    ttr_prefix<<<128, 256, 0, stream>>>(ST);
    ttr_main<<<BH * NCH, 512, 0, stream>>>(q, k, v, ST, out);
}